// Round 3
// baseline (184.926 us; speedup 1.0000x reference)
//
#include <hip/hip_runtime.h>

#define GXc 96
#define GYc 96
#define RFc 24
#define Bc 8
#define Nc (GXc * GYc)          // 9216
#define Hc (GXc - 1 + RFc)      // 119
#define IN_IMG (Hc * Hc)        // 14161
#define RF2 (RFc * RFc)         // 576
#define GAMMA 0.9f
#define INV_GAMMA (1.0f / 0.9f)

#define ROWS 2                  // output rows per wave (halved: more waves resident)
#define WAVES_PER_BLOCK 4
#define ROWS_PER_BLOCK (ROWS * WAVES_PER_BLOCK)   // 8
#define NBLOCKS (Nc / ROWS_PER_BLOCK)             // 1152
#define KITERS (Nc / 256)                         // 36 (256 k-elems per wave-iter)

__global__ __launch_bounds__(256, 4) void cortex_fused_kernel(
    const float* __restrict__ input,   // (B, 119, 119)
    const float* __restrict__ prev,    // (B, N)
    const float* __restrict__ aw,      // (96, 96, 24, 24) = (N, 576)
    const float* __restrict__ We,      // (N, N)
    const float* __restrict__ Wi,      // (N, N)
    float* __restrict__ out)           // (B, N)
{
    const int tid  = threadIdx.x;
    const int wave = tid >> 6;
    const int lane = tid & 63;
    const int rowbase = blockIdx.x * ROWS_PER_BLOCK + wave * ROWS;

    // acc[r][b] accumulates (afferent/GAMMA) + prev@(We-Wi)^T partials.
    float acc[ROWS][Bc];
#pragma unroll
    for (int r = 0; r < ROWS; ++r)
#pragma unroll
        for (int b = 0; b < Bc; ++b) acc[r][b] = 0.f;

    // ---------------- afferent (local RF conv), all-lane k layout ----------
    // lane handles rf-elements hw = t*64 + lane; pre-scaled by 1/GAMMA so the
    // single epilogue multiply by GAMMA restores it.
#pragma unroll
    for (int r = 0; r < ROWS; ++r) {
        const int n  = rowbase + r;
        const int gi = n / GYc;
        const int gj = n - gi * GYc;
        const float* awn = aw + (size_t)n * RF2;
        const int base = gi * Hc + gj;
#pragma unroll
        for (int t = 0; t < RF2 / 64; ++t) {   // 9 iters
            const int hw = t * 64 + lane;
            const int h  = hw / RFc;
            const int w  = hw - h * RFc;
            const float av  = awn[hw] * INV_GAMMA;
            const int  off  = base + h * Hc + w;
#pragma unroll
            for (int b = 0; b < Bc; ++b)
                acc[r][b] += input[b * IN_IMG + off] * av;
        }
    }

    // ---------------- lateral: prev @ (We - Wi)^T, full-wave coalesced -----
    const int koff = lane * 4;
    for (int j = 0; j < KITERS; ++j) {
        const int k0 = j * 256 + koff;

        // issue all W loads first (coalesced 1KB segments in flight)
        float4 we4[ROWS], wi4[ROWS];
#pragma unroll
        for (int r = 0; r < ROWS; ++r) {
            const size_t ro = (size_t)(rowbase + r) * Nc + k0;
            we4[r] = *(const float4*)(We + ro);
            wi4[r] = *(const float4*)(Wi + ro);
        }
        // prev tiles (L2-resident, coalesced per-b)
        float4 p[Bc];
#pragma unroll
        for (int b = 0; b < Bc; ++b)
            p[b] = *(const float4*)(prev + b * Nc + k0);

#pragma unroll
        for (int r = 0; r < ROWS; ++r) {
            const float4 w4 = make_float4(we4[r].x - wi4[r].x,
                                          we4[r].y - wi4[r].y,
                                          we4[r].z - wi4[r].z,
                                          we4[r].w - wi4[r].w);
#pragma unroll
            for (int b = 0; b < Bc; ++b)
                acc[r][b] += w4.x * p[b].x + w4.y * p[b].y
                           + w4.z * p[b].z + w4.w * p[b].w;
        }
    }

    // ---------------- full-wave butterfly reduce + epilogue ----------------
#pragma unroll
    for (int r = 0; r < ROWS; ++r)
#pragma unroll
        for (int b = 0; b < Bc; ++b) {
            float v = acc[r][b];
            v += __shfl_xor(v, 1);
            v += __shfl_xor(v, 2);
            v += __shfl_xor(v, 4);
            v += __shfl_xor(v, 8);
            v += __shfl_xor(v, 16);
            v += __shfl_xor(v, 32);
            acc[r][b] = v;
        }

#pragma unroll
    for (int r = 0; r < ROWS; ++r)
#pragma unroll
        for (int b = 0; b < Bc; ++b)
            if (lane == b * ROWS_PER_BLOCK / WAVES_PER_BLOCK + r) {   // lane == b*2+r fits 0..15... see below
                // NOTE: mapping must be a bijection lane -> (r,b) pair; use b*ROWS+r
            }

    // (clean bijective epilogue: lane l in [0, ROWS*Bc) owns (r = l % ROWS, b = l / ROWS))
    {
        const int l = lane;
        if (l < ROWS * Bc) {
            const int r = l % ROWS;
            const int b = l / ROWS;
            const float tot = GAMMA * acc[r][b];
            out[b * Nc + rowbase + r] = tot > 0.f ? tot : 0.f;
        }
    }
}

extern "C" void kernel_launch(void* const* d_in, const int* in_sizes, int n_in,
                              void* d_out, int out_size, void* d_ws, size_t ws_size,
                              hipStream_t stream) {
    const float* input = (const float*)d_in[0];
    const float* prev  = (const float*)d_in[1];
    const float* aw    = (const float*)d_in[2];
    const float* We    = (const float*)d_in[3];
    const float* Wi    = (const float*)d_in[4];
    // d_in[5], d_in[6] are rf_x / rf_y == arange(96): identity, folded into indexing.
    float* out = (float*)d_out;

    cortex_fused_kernel<<<NBLOCKS, 256, 0, stream>>>(input, prev, aw, We, Wi, out);
}

// Round 4
// 149.620 us; speedup vs baseline: 1.2360x; 1.2360x over previous
//
#include <hip/hip_runtime.h>

#define GXc 96
#define GYc 96
#define RFc 24
#define Bc 8
#define Nc (GXc * GYc)          // 9216
#define Hc (GXc - 1 + RFc)      // 119
#define IN_IMG (Hc * Hc)        // 14161
#define RF2 (RFc * RFc)         // 576
#define GAMMA 0.9f
#define INV_GAMMA (1.0f / 0.9f)

#define ROWS 2                  // output rows per wave
#define WAVES_PER_BLOCK 4
#define ROWS_PER_BLOCK (ROWS * WAVES_PER_BLOCK)   // 8
#define NBLOCKS (Nc / ROWS_PER_BLOCK)             // 1152
#define KW 256                                    // k-window (floats)
#define KITERS (Nc / KW)                          // 36

__global__ __launch_bounds__(256) void cortex_fused_kernel(
    const float* __restrict__ input,   // (B, 119, 119)
    const float* __restrict__ prev,    // (B, N)
    const float* __restrict__ aw,      // (N, 576)
    const float* __restrict__ We,      // (N, N)
    const float* __restrict__ Wi,      // (N, N)
    float* __restrict__ out)           // (B, N)
{
    __shared__ float pv[2][Bc][KW];    // double-buffered prev k-window, 16 KB

    const int tid  = threadIdx.x;
    const int wave = tid >> 6;
    const int lane = tid & 63;
    const int rowbase = blockIdx.x * ROWS_PER_BLOCK + wave * ROWS;
    const int koff = lane << 2;        // float4 slot within window
    const int b0 = wave * 2;           // each wave stages 2 batches of the window
    const int b1 = wave * 2 + 1;

    float acc[ROWS][Bc];
#pragma unroll
    for (int r = 0; r < ROWS; ++r)
#pragma unroll
        for (int b = 0; b < Bc; ++b) acc[r][b] = 0.f;

    // ---------------- afferent (local RF conv), all-lane k layout ----------
#pragma unroll
    for (int r = 0; r < ROWS; ++r) {
        const int n  = rowbase + r;
        const int gi = n / GYc;
        const int gj = n - gi * GYc;
        const float* awn = aw + (size_t)n * RF2;
        const int base = gi * Hc + gj;
#pragma unroll
        for (int t = 0; t < RF2 / 64; ++t) {   // 9 iters
            const int hw = t * 64 + lane;
            const int h  = hw / RFc;
            const int w  = hw - h * RFc;
            const float av  = awn[hw] * INV_GAMMA;
            const int  off  = base + h * Hc + w;
#pragma unroll
            for (int b = 0; b < Bc; ++b)
                acc[r][b] += input[b * IN_IMG + off] * av;
        }
    }

    // ---------------- lateral: prev @ (We - Wi)^T, software-pipelined ------
    // Prologue: stage window 0 into LDS buf 0, W rows window 0 into regs.
    float4 t0 = *(const float4*)(prev + b0 * Nc + koff);
    float4 t1 = *(const float4*)(prev + b1 * Nc + koff);
    float4 weC[ROWS], wiC[ROWS];
#pragma unroll
    for (int r = 0; r < ROWS; ++r) {
        const size_t ro = (size_t)(rowbase + r) * Nc + koff;
        weC[r] = *(const float4*)(We + ro);
        wiC[r] = *(const float4*)(Wi + ro);
    }
    *(float4*)&pv[0][b0][koff] = t0;
    *(float4*)&pv[0][b1][koff] = t1;
    __syncthreads();

    int cur = 0;
    for (int j = 0; j < KITERS - 1; ++j) {
        const int k1 = (j + 1) * KW + koff;

        // issue next-window loads first (latency hidden under compute below)
        const float4 nt0 = *(const float4*)(prev + b0 * Nc + k1);
        const float4 nt1 = *(const float4*)(prev + b1 * Nc + k1);
        float4 weN[ROWS], wiN[ROWS];
#pragma unroll
        for (int r = 0; r < ROWS; ++r) {
            const size_t ro = (size_t)(rowbase + r) * Nc + k1;
            weN[r] = *(const float4*)(We + ro);
            wiN[r] = *(const float4*)(Wi + ro);
        }

        // compute current window from LDS + current W regs
        float4 wd[ROWS];
#pragma unroll
        for (int r = 0; r < ROWS; ++r)
            wd[r] = make_float4(weC[r].x - wiC[r].x, weC[r].y - wiC[r].y,
                                weC[r].z - wiC[r].z, weC[r].w - wiC[r].w);
#pragma unroll
        for (int b = 0; b < Bc; ++b) {
            const float4 p = *(const float4*)&pv[cur][b][koff];
#pragma unroll
            for (int r = 0; r < ROWS; ++r)
                acc[r][b] += wd[r].x * p.x + wd[r].y * p.y
                           + wd[r].z * p.z + wd[r].w * p.w;
        }

        // stage next window into the other LDS buffer; rotate W regs
        *(float4*)&pv[cur ^ 1][b0][koff] = nt0;
        *(float4*)&pv[cur ^ 1][b1][koff] = nt1;
#pragma unroll
        for (int r = 0; r < ROWS; ++r) { weC[r] = weN[r]; wiC[r] = wiN[r]; }
        __syncthreads();
        cur ^= 1;
    }

    // final (peeled) window
    {
        float4 wd[ROWS];
#pragma unroll
        for (int r = 0; r < ROWS; ++r)
            wd[r] = make_float4(weC[r].x - wiC[r].x, weC[r].y - wiC[r].y,
                                weC[r].z - wiC[r].z, weC[r].w - wiC[r].w);
#pragma unroll
        for (int b = 0; b < Bc; ++b) {
            const float4 p = *(const float4*)&pv[cur][b][koff];
#pragma unroll
            for (int r = 0; r < ROWS; ++r)
                acc[r][b] += wd[r].x * p.x + wd[r].y * p.y
                           + wd[r].z * p.z + wd[r].w * p.w;
        }
    }

    // ---------------- butterfly reduce + static-index epilogue -------------
#pragma unroll
    for (int r = 0; r < ROWS; ++r)
#pragma unroll
        for (int b = 0; b < Bc; ++b) {
            float v = acc[r][b];
            v += __shfl_xor(v, 1);
            v += __shfl_xor(v, 2);
            v += __shfl_xor(v, 4);
            v += __shfl_xor(v, 8);
            v += __shfl_xor(v, 16);
            v += __shfl_xor(v, 32);
            if (lane == b * ROWS + r) {          // compile-time constant per instance
                const float tot = GAMMA * v;
                out[b * Nc + rowbase + r] = tot > 0.f ? tot : 0.f;
            }
        }
}

extern "C" void kernel_launch(void* const* d_in, const int* in_sizes, int n_in,
                              void* d_out, int out_size, void* d_ws, size_t ws_size,
                              hipStream_t stream) {
    const float* input = (const float*)d_in[0];
    const float* prev  = (const float*)d_in[1];
    const float* aw    = (const float*)d_in[2];
    const float* We    = (const float*)d_in[3];
    const float* Wi    = (const float*)d_in[4];
    // d_in[5], d_in[6] are rf_x / rf_y == arange(96): identity, folded into indexing.
    float* out = (float*)d_out;

    cortex_fused_kernel<<<NBLOCKS, 256, 0, stream>>>(input, prev, aw, We, Wi, out);
}